// Round 11
// baseline (25.767 us; speedup 1.0000x reference)
//
#include <hip/hip_runtime.h>
#include <math.h>

// ws float layout (2.4 KB)
#define WS_STATS 0      // 13 floats: vw, cov[6], vc[6]
#define WS_T     16     // 576 floats: D8[8*64] | VD[8*8]

__constant__ float FREQ_BIAS[36] = {
    0.0f, 0.05f, 0.0f, 0.0f, 0.0f, 0.0f,
    0.05f, 0.0f, 0.1f, 0.05f, 0.0f, 0.0f,
    0.0f, 0.1f, 0.0f, 0.1f, 0.0f, 0.0f,
    0.0f, 0.05f, 0.1f, 0.0f, 0.1f, 0.0f,
    0.0f, 0.0f, 0.0f, 0.1f, 0.0f, 0.1f,
    0.0f, 0.0f, 0.0f, 0.0f, 0.1f, 0.0f
};

// kH: per-head full pipeline (fold + 3 matvec passes + tables).
// 8 blocks (one per head) x 1024 threads (16 waves).
__global__ __launch_bounds__(1024) void kH(
    const float* __restrict__ W_in, const float* __restrict__ b_in,
    const float* __restrict__ gamma, const float* __restrict__ beta,
    const float* __restrict__ Wq, const float* __restrict__ bq,
    const float* __restrict__ Wk, const float* __restrict__ bk,
    const float* __restrict__ Wv, const float* __restrict__ bv,
    const float* __restrict__ Wo,
    float* __restrict__ ws)
{
    __shared__ float ls8[512][8];        // fold vectors [row][v]  (16 KB)
    __shared__ float partial[16][8][64]; // wave partials         (32 KB)
    __shared__ float ab[24][65];         // head's AB slice       (6.2 KB)
    __shared__ float red[13][8];

    const int tid = threadIdx.x, wave = tid >> 6, lane = tid & 63;
    const int h = blockIdx.x;

    // ---- fold phase (threads 0..511 active) ----
    float wd = 0.f, gm = 0.f, bt = 0.f, c[6];
    if (tid < 512) {
        const float k_ln = 0.0179889457300305367f;  // ln(10000)/512
        const float freqs[6] = {0.2f, 0.4f, 0.6f, 0.8f, 1.0f, 0.0f};
        wd = W_in[tid]; gm = gamma[tid]; bt = beta[tid];
        const float bi = b_in[tid];
        const float dv = __expf(-(float)(tid & ~1) * k_ln);
        const bool odd = (tid & 1);
        #pragma unroll
        for (int s = 0; s < 6; ++s) {
            float ph = freqs[s] * dv;
            c[s] = bi + (odd ? __cosf(ph) : __sinf(ph));
        }
        float sums[7];
        sums[0] = wd;
        #pragma unroll
        for (int s = 0; s < 6; ++s) sums[1 + s] = c[s];
        #pragma unroll
        for (int m = 1; m < 64; m <<= 1) {
            #pragma unroll
            for (int k = 0; k < 7; ++k) sums[k] += __shfl_xor(sums[k], m, 64);
        }
        if (lane == 0) {
            #pragma unroll
            for (int k = 0; k < 7; ++k) red[k][wave] = sums[k];
        }
    }
    __syncthreads();
    float mw = 0.f, mc[6];
    {
        float t = 0.f;
        #pragma unroll
        for (int j = 0; j < 8; ++j) t += red[0][j];
        mw = t * (1.0f / 512.0f);
        #pragma unroll
        for (int s = 0; s < 6; ++s) {
            t = 0.f;
            #pragma unroll
            for (int j = 0; j < 8; ++j) t += red[1 + s][j];
            mc[s] = t * (1.0f / 512.0f);
        }
    }
    __syncthreads();
    if (tid < 512) {
        const float hw = wd - mw;
        float hc[6];
        #pragma unroll
        for (int s = 0; s < 6; ++s) hc[s] = c[s] - mc[s];
        float moms[13];
        moms[0] = hw * hw;
        #pragma unroll
        for (int s = 0; s < 6; ++s) { moms[1 + s] = hw * hc[s]; moms[7 + s] = hc[s] * hc[s]; }
        #pragma unroll
        for (int m = 1; m < 64; m <<= 1) {
            #pragma unroll
            for (int k = 0; k < 13; ++k) moms[k] += __shfl_xor(moms[k], m, 64);
        }
        if (lane == 0) {
            #pragma unroll
            for (int k = 0; k < 13; ++k) red[k][wave] = moms[k];
        }
        ls8[tid][0] = hw * gm;
        #pragma unroll
        for (int s = 0; s < 6; ++s) ls8[tid][1 + s] = hc[s] * gm;
        ls8[tid][7] = bt;
    }
    __syncthreads();
    if (h == 0 && tid < 13) {
        float t = 0.f;
        #pragma unroll
        for (int j = 0; j < 8; ++j) t += red[tid][j];
        ws[WS_STATS + tid] = t * (1.0f / 512.0f);
    }

    // ---- 3 matvec passes: q, k, v (wave = 32 rows, lane = col) ----
    const int colg = (h << 6) | lane;
    const int row0 = wave << 5;
    #pragma unroll
    for (int p = 0; p < 3; ++p) {
        const float* W  = (p == 0) ? Wq : ((p == 1) ? Wk : Wv);
        const float* bb = (p == 0) ? bq : ((p == 1) ? bk : bv);

        float acc[8] = {0.f, 0.f, 0.f, 0.f, 0.f, 0.f, 0.f, 0.f};
        #pragma unroll 8
        for (int rr = 0; rr < 32; ++rr) {
            const int row = row0 + rr;
            const float wv = W[row * 512 + colg];
            const float4 f0 = *(const float4*)&ls8[row][0];
            const float4 f1 = *(const float4*)&ls8[row][4];
            acc[0] = fmaf(wv, f0.x, acc[0]);
            acc[1] = fmaf(wv, f0.y, acc[1]);
            acc[2] = fmaf(wv, f0.z, acc[2]);
            acc[3] = fmaf(wv, f0.w, acc[3]);
            acc[4] = fmaf(wv, f1.x, acc[4]);
            acc[5] = fmaf(wv, f1.y, acc[5]);
            acc[6] = fmaf(wv, f1.z, acc[6]);
            acc[7] = fmaf(wv, f1.w, acc[7]);
        }
        #pragma unroll
        for (int v = 0; v < 8; ++v) partial[wave][v][lane] = acc[v];
        __syncthreads();
        if (tid < 512) {
            const int v = tid >> 6, cx = tid & 63;
            float t = 0.f;
            #pragma unroll
            for (int w = 0; w < 16; ++w) t += partial[w][v][cx];
            if (v == 7) t += bb[(h << 6) | cx];
            ab[p * 8 + v][cx] = t;
        }
        __syncthreads();
    }

    // ---- tables: D8[h] via 512 threads (64 entries x 8 segs), VD[h] via 64 ----
    if (tid < 512) {
        const int entry = tid >> 3, seg = tid & 7;
        const int a = entry >> 3, b2 = entry & 7;
        const int c0 = seg << 3;
        float t = 0.f;
        #pragma unroll
        for (int c = 0; c < 8; ++c)
            t = fmaf(ab[a][c0 + c], ab[8 + b2][c0 + c], t);
        t += __shfl_xor(t, 1, 64);
        t += __shfl_xor(t, 2, 64);
        t += __shfl_xor(t, 4, 64);
        if (seg == 0) ws[WS_T + (h << 6) + entry] = t * 0.125f;  // fold hd^-0.5
    } else if (tid < 576) {
        const int u = tid - 512;
        const int a = u >> 3, seg = u & 7;
        const int c0 = seg << 3;
        float t = 0.f;
        #pragma unroll
        for (int c = 0; c < 8; ++c)
            t = fmaf(ab[16 + a][c0 + c], Wo[(h << 6) + c0 + c], t);
        t += __shfl_xor(t, 1, 64);
        t += __shfl_xor(t, 2, 64);
        t += __shfl_xor(t, 4, 64);
        if (seg == 0) ws[WS_T + 512 + (h << 3) + a] = t;
    }
}

// kC: main attention. 384 blocks x 256 threads, one (b,i) per thread.
__global__ __launch_bounds__(256) void kC(const float* __restrict__ x,
                                          const float* __restrict__ ws,
                                          const float* __restrict__ bo,
                                          float* __restrict__ out, int total)
{
    __shared__ float T_s[592];   // D8[512] | VD[64] | stats[13]
    const int tid = threadIdx.x;
    for (int e = tid; e < 589; e += 256)
        T_s[e] = (e < 576) ? ws[WS_T + e] : ws[WS_STATS + (e - 576)];
    __syncthreads();

    const int g = blockIdx.x * 256 + tid;
    if (g >= total) return;
    const unsigned b = (unsigned)g / 6u;
    const int i = g - (int)b * 6;

    const float* D8 = T_s;
    const float* VD = T_s + 512;
    const float vw = T_s[576];
    const float* cov = T_s + 577;
    const float* vc = T_s + 583;
    const float bo0 = bo[0];

    const float2* xp = (const float2*)(x + (size_t)b * 6u);
    const float2 x01 = xp[0], x23 = xp[1], x45 = xp[2];
    const float al[6] = {x01.x, x01.y, x23.x, x23.y, x45.x, x45.y};

    float r[6], u[6];
    #pragma unroll
    for (int j = 0; j < 6; ++j) {
        float a = al[j];
        float var = fmaf(a, fmaf(a, vw, 2.0f * cov[j]), vc[j]) + 1e-5f;
        r[j] = rsqrtf(var);
        u[j] = a * r[j];
    }
    float bias[6];
    #pragma unroll
    for (int j = 0; j < 6; ++j) bias[j] = FREQ_BIAS[i * 6 + j];

    const float r_i = r[i], u_i = u[i];
    float acc = 0.f;
    float am[6] = {0.f, 0.f, 0.f, 0.f, 0.f, 0.f};

    #pragma unroll
    for (int h = 0; h < 8; ++h) {
        const float* Dh = D8 + h * 64;
        const float* Vh = VD + h * 8;
        const float P1 = Dh[0], P5 = Dh[7], P7 = Dh[56], P9 = Dh[63];
        const float P3i = Dh[(1 + i) * 8], P6i = Dh[(1 + i) * 8 + 7];

        float s[6];
        #pragma unroll
        for (int j = 0; j < 6; ++j) {
            float t1 = fmaf(u[j], P1, fmaf(r[j], Dh[1 + j], P5));
            float t2 = fmaf(u[j], P3i, fmaf(r[j], Dh[(1 + i) * 8 + 1 + j], P6i));
            float t3 = fmaf(u[j], P7, fmaf(r[j], Dh[57 + j], P9));
            s[j] = fmaf(u_i, t1, fmaf(r_i, t2, t3)) + bias[j];
        }
        float m = s[0];
        #pragma unroll
        for (int j = 1; j < 6; ++j) m = fmaxf(m, s[j]);
        float e[6], ssum = 0.f;
        #pragma unroll
        for (int j = 0; j < 6; ++j) { e[j] = __expf(s[j] - m); ssum += e[j]; }
        const float inv = 1.0f / ssum;

        const float av = Vh[0], cvv = Vh[7];
        float ha = 0.f;
        #pragma unroll
        for (int j = 0; j < 6; ++j) {
            float a = e[j] * inv;
            am[j] += a;
            float vp = fmaf(u[j], av, r[j] * Vh[1 + j]);
            ha = fmaf(a, vp, ha);
        }
        acc += ha + cvv;
    }

    out[g] = acc + bo0 + al[i];
    float2* amp = (float2*)(out + total + (size_t)g * 6u);
    amp[0] = make_float2(am[0] * 0.125f, am[1] * 0.125f);
    amp[1] = make_float2(am[2] * 0.125f, am[3] * 0.125f);
    amp[2] = make_float2(am[4] * 0.125f, am[5] * 0.125f);
}

extern "C" void kernel_launch(void* const* d_in, const int* in_sizes, int n_in,
                              void* d_out, int out_size, void* d_ws, size_t ws_size,
                              hipStream_t stream) {
    const float* x     = (const float*)d_in[0];
    const float* W_in  = (const float*)d_in[1];
    const float* b_in  = (const float*)d_in[2];
    const float* Wq    = (const float*)d_in[3];
    const float* bq    = (const float*)d_in[4];
    const float* Wk    = (const float*)d_in[5];
    const float* bk    = (const float*)d_in[6];
    const float* Wv    = (const float*)d_in[7];
    const float* bv    = (const float*)d_in[8];
    const float* Wo    = (const float*)d_in[9];
    const float* bo    = (const float*)d_in[10];
    const float* gamma = (const float*)d_in[11];
    const float* beta  = (const float*)d_in[12];
    float* ws  = (float*)d_ws;
    float* out = (float*)d_out;

    const int total = in_sizes[0];  // B*6 = 98304

    kH<<<8, 1024, 0, stream>>>(W_in, b_in, gamma, beta, Wq, bq, Wk, bk, Wv, bv, Wo, ws);
    kC<<<(total + 255) / 256, 256, 0, stream>>>(x, ws, bo, out, total);
}

// Round 12
// 18.996 us; speedup vs baseline: 1.3565x; 1.3565x over previous
//
#include <hip/hip_runtime.h>
#include <math.h>

// ws float layout
#define WS_STATS 0     // 13 floats: vw, cov[6], vc[6]
#define WS_T     16    // 576 floats: D8[8*64] | VD[8*8]
// matvec partials (192*512 floats) live in d_out[0..98303]; kC overwrites them.

__constant__ float FREQ_BIAS[36] = {
    0.0f, 0.05f, 0.0f, 0.0f, 0.0f, 0.0f,
    0.05f, 0.0f, 0.1f, 0.05f, 0.0f, 0.0f,
    0.0f, 0.1f, 0.0f, 0.1f, 0.0f, 0.0f,
    0.0f, 0.05f, 0.1f, 0.0f, 0.1f, 0.0f,
    0.0f, 0.0f, 0.0f, 0.1f, 0.0f, 0.1f,
    0.0f, 0.0f, 0.0f, 0.0f, 0.1f, 0.0f
};

// kA: LN-fold + matvec partials, W prefetched BEFORE the fold phase.
// 192 blocks (p,cg,rc) x 256 threads.
__global__ __launch_bounds__(256) void kA(
    const float* __restrict__ W_in, const float* __restrict__ b_in,
    const float* __restrict__ gamma, const float* __restrict__ beta,
    const float* __restrict__ Wq, const float* __restrict__ bq,
    const float* __restrict__ Wk, const float* __restrict__ bk,
    const float* __restrict__ Wv, const float* __restrict__ bv,
    float* __restrict__ ws, float* __restrict__ part)
{
    __shared__ float ls8[512][8];        // folded vectors [row][v]
    __shared__ float partial[4][8][64];  // [wave][vec][col]
    __shared__ float red[13][4];

    const int tid = threadIdx.x, wave = tid >> 6, lane = tid & 63;
    const int bid = blockIdx.x;
    const int rc = bid & 7, cg = (bid >> 3) & 7, p = bid >> 6;

    // ---- issue 16 independent W loads FIRST (latency hides under fold) ----
    const float* W  = (p == 0) ? Wq : ((p == 1) ? Wk : Wv);
    const float* bb = (p == 0) ? bq : ((p == 1) ? bk : bv);
    const int col = (cg << 6) | lane;
    const int row0 = (rc << 6) | (wave << 4);
    float wreg[16];
    #pragma unroll
    for (int rr = 0; rr < 16; ++rr)
        wreg[rr] = W[(row0 + rr) * 512 + col];

    // ---- fold phase (runs while W loads are in flight) ----
    const float k_ln = 0.0179889457300305367f;  // ln(10000)/512
    const float freqs[6] = {0.2f, 0.4f, 0.6f, 0.8f, 1.0f, 0.0f};
    float wd[2], cc2[2][6], gm[2], bt[2];
    #pragma unroll
    for (int q = 0; q < 2; ++q) {
        const int d = tid + q * 256;
        wd[q] = W_in[d];
        gm[q] = gamma[d];
        bt[q] = beta[d];
        float dv = __expf(-(float)(d & ~1) * k_ln);
        float bi = b_in[d];
        bool odd = (d & 1);
        #pragma unroll
        for (int s = 0; s < 6; ++s) {
            float ph = freqs[s] * dv;
            cc2[q][s] = bi + (odd ? __cosf(ph) : __sinf(ph));
        }
    }
    {   // means of w and c_s
        float sums[7];
        sums[0] = wd[0] + wd[1];
        #pragma unroll
        for (int s = 0; s < 6; ++s) sums[1 + s] = cc2[0][s] + cc2[1][s];
        #pragma unroll
        for (int m = 1; m < 64; m <<= 1) {
            #pragma unroll
            for (int k = 0; k < 7; ++k) sums[k] += __shfl_xor(sums[k], m, 64);
        }
        if (lane == 0) {
            #pragma unroll
            for (int k = 0; k < 7; ++k) red[k][wave] = sums[k];
        }
    }
    __syncthreads();
    const float mw = (red[0][0] + red[0][1] + red[0][2] + red[0][3]) * (1.0f / 512.0f);
    float mc[6];
    #pragma unroll
    for (int s = 0; s < 6; ++s)
        mc[s] = (red[1 + s][0] + red[1 + s][1] + red[1 + s][2] + red[1 + s][3]) * (1.0f / 512.0f);
    __syncthreads();

    float hw[2], hc[2][6];
    #pragma unroll
    for (int q = 0; q < 2; ++q) {
        hw[q] = wd[q] - mw;
        #pragma unroll
        for (int s = 0; s < 6; ++s) hc[q][s] = cc2[q][s] - mc[s];
    }

    // moments/stats: block 0 only
    if (bid == 0) {
        float moms[13];
        moms[0] = hw[0] * hw[0] + hw[1] * hw[1];
        #pragma unroll
        for (int s = 0; s < 6; ++s) {
            moms[1 + s] = hw[0] * hc[0][s] + hw[1] * hc[1][s];
            moms[7 + s] = hc[0][s] * hc[0][s] + hc[1][s] * hc[1][s];
        }
        #pragma unroll
        for (int m = 1; m < 64; m <<= 1) {
            #pragma unroll
            for (int k = 0; k < 13; ++k) moms[k] += __shfl_xor(moms[k], m, 64);
        }
        if (lane == 0) {
            #pragma unroll
            for (int k = 0; k < 13; ++k) red[k][wave] = moms[k];
        }
    }
    // folded vectors
    #pragma unroll
    for (int q = 0; q < 2; ++q) {
        const int d = tid + q * 256;
        ls8[d][0] = hw[q] * gm[q];
        #pragma unroll
        for (int s = 0; s < 6; ++s) ls8[d][1 + s] = hc[q][s] * gm[q];
        ls8[d][7] = bt[q];
    }
    __syncthreads();
    if (bid == 0 && tid < 13)
        ws[WS_STATS + tid] = (red[tid][0] + red[tid][1] + red[tid][2] + red[tid][3]) * (1.0f / 512.0f);

    // ---- matvec from prefetched W regs + LDS fold reads ----
    float acc[8] = {0.f, 0.f, 0.f, 0.f, 0.f, 0.f, 0.f, 0.f};
    #pragma unroll
    for (int rr = 0; rr < 16; ++rr) {
        const int row = row0 + rr;
        const float wv = wreg[rr];
        const float4 f0 = *(const float4*)&ls8[row][0];
        const float4 f1 = *(const float4*)&ls8[row][4];
        acc[0] = fmaf(wv, f0.x, acc[0]);
        acc[1] = fmaf(wv, f0.y, acc[1]);
        acc[2] = fmaf(wv, f0.z, acc[2]);
        acc[3] = fmaf(wv, f0.w, acc[3]);
        acc[4] = fmaf(wv, f1.x, acc[4]);
        acc[5] = fmaf(wv, f1.y, acc[5]);
        acc[6] = fmaf(wv, f1.z, acc[6]);
        acc[7] = fmaf(wv, f1.w, acc[7]);
    }
    #pragma unroll
    for (int v = 0; v < 8; ++v) partial[wave][v][lane] = acc[v];
    __syncthreads();
    #pragma unroll
    for (int ii = 0; ii < 2; ++ii) {
        const int idx = tid + ii * 256;
        const int v = idx >> 6, cx = idx & 63;
        float t = partial[0][v][cx] + partial[1][v][cx]
                + partial[2][v][cx] + partial[3][v][cx];
        if (v == 7 && rc == 0) t += bb[(cg << 6) | cx];
        part[(size_t)bid * 512 + idx] = t;
    }
}

// kB: reduce partials + dot tables. 8 blocks (one per head) x 256 threads.
__global__ __launch_bounds__(256) void kB(const float* __restrict__ part,
                                          const float* __restrict__ Wo,
                                          float* __restrict__ ws)
{
    __shared__ float ab[24][65];
    const int tid = threadIdx.x;
    const int h = blockIdx.x;

    // 24 vp x 16 float4 = 384 vector-loads, 2 rounds x 192... (12/thread)
    for (int e4 = tid; e4 < 24 * 16; e4 += 256) {
        const int vp = e4 >> 4, c4 = (e4 & 15) << 2;
        const int p = vp >> 3, v = vp & 7;
        const int stripe = p * 8 + h;
        float4 s = make_float4(0.f, 0.f, 0.f, 0.f);
        #pragma unroll
        for (int rcx = 0; rcx < 8; ++rcx) {
            const float4 t4 = *(const float4*)&part[(size_t)(stripe * 8 + rcx) * 512 + v * 64 + c4];
            s.x += t4.x; s.y += t4.y; s.z += t4.z; s.w += t4.w;
        }
        ab[vp][c4]     = s.x;
        ab[vp][c4 + 1] = s.y;
        ab[vp][c4 + 2] = s.z;
        ab[vp][c4 + 3] = s.w;
    }
    __syncthreads();

    if (tid < 64) {
        const int a = tid >> 3, b2 = tid & 7;
        float acc = 0.f;
        #pragma unroll
        for (int c = 0; c < 64; ++c)
            acc = fmaf(ab[a][c], ab[8 + b2][c], acc);
        ws[WS_T + (h << 6) + tid] = acc * 0.125f;   // fold hd^-0.5
    } else if (tid < 72) {
        const int a = tid - 64;
        float acc = 0.f;
        #pragma unroll
        for (int c = 0; c < 64; ++c)
            acc = fmaf(ab[16 + a][c], Wo[(h << 6) + c], acc);
        ws[WS_T + 512 + (h << 3) + a] = acc;
    }
}

// kC: main attention. 384 blocks x 256 threads, one (b,i) per thread.
__global__ __launch_bounds__(256) void kC(const float* __restrict__ x,
                                          const float* __restrict__ ws,
                                          const float* __restrict__ bo,
                                          float* __restrict__ out, int total)
{
    __shared__ float T_s[592];   // D8[512] | VD[64] | stats[13]
    const int tid = threadIdx.x;
    if (tid < 144)
        *(float4*)&T_s[tid << 2] = *(const float4*)&ws[WS_T + (tid << 2)];
    else if (tid < 157)
        T_s[576 + tid - 144] = ws[WS_STATS + tid - 144];
    __syncthreads();

    const int g = blockIdx.x * 256 + tid;
    if (g >= total) return;
    const unsigned b = (unsigned)g / 6u;
    const int i = g - (int)b * 6;

    const float* D8 = T_s;
    const float* VD = T_s + 512;
    const float vw = T_s[576];
    const float* cov = T_s + 577;
    const float* vc = T_s + 583;
    const float bo0 = bo[0];

    const float2* xp = (const float2*)(x + (size_t)b * 6u);
    const float2 x01 = xp[0], x23 = xp[1], x45 = xp[2];
    const float al[6] = {x01.x, x01.y, x23.x, x23.y, x45.x, x45.y};

    float r[6], u[6];
    #pragma unroll
    for (int j = 0; j < 6; ++j) {
        float a = al[j];
        float var = fmaf(a, fmaf(a, vw, 2.0f * cov[j]), vc[j]) + 1e-5f;
        r[j] = rsqrtf(var);
        u[j] = a * r[j];
    }
    float bias[6];
    #pragma unroll
    for (int j = 0; j < 6; ++j) bias[j] = FREQ_BIAS[i * 6 + j];

    const float r_i = r[i], u_i = u[i];
    float acc = 0.f;
    float am[6] = {0.f, 0.f, 0.f, 0.f, 0.f, 0.f};

    #pragma unroll
    for (int h = 0; h < 8; ++h) {
        const float* Dh = D8 + h * 64;
        const float* Vh = VD + h * 8;
        const float P1 = Dh[0], P5 = Dh[7], P7 = Dh[56], P9 = Dh[63];
        const float P3i = Dh[(1 + i) * 8], P6i = Dh[(1 + i) * 8 + 7];

        float s[6];
        #pragma unroll
        for (int j = 0; j < 6; ++j) {
            float t1 = fmaf(u[j], P1, fmaf(r[j], Dh[1 + j], P5));
            float t2 = fmaf(u[j], P3i, fmaf(r[j], Dh[(1 + i) * 8 + 1 + j], P6i));
            float t3 = fmaf(u[j], P7, fmaf(r[j], Dh[57 + j], P9));
            s[j] = fmaf(u_i, t1, fmaf(r_i, t2, t3)) + bias[j];
        }
        float m = s[0];
        #pragma unroll
        for (int j = 1; j < 6; ++j) m = fmaxf(m, s[j]);
        float e[6], ssum = 0.f;
        #pragma unroll
        for (int j = 0; j < 6; ++j) { e[j] = __expf(s[j] - m); ssum += e[j]; }
        const float inv = 1.0f / ssum;

        const float av = Vh[0], cvv = Vh[7];
        float ha = 0.f;
        #pragma unroll
        for (int j = 0; j < 6; ++j) {
            float a = e[j] * inv;
            am[j] += a;
            float vp = fmaf(u[j], av, r[j] * Vh[1 + j]);
            ha = fmaf(a, vp, ha);
        }
        acc += ha + cvv;
    }

    out[g] = acc + bo0 + al[i];
    float2* amp = (float2*)(out + total + (size_t)g * 6u);
    amp[0] = make_float2(am[0] * 0.125f, am[1] * 0.125f);
    amp[1] = make_float2(am[2] * 0.125f, am[3] * 0.125f);
    amp[2] = make_float2(am[4] * 0.125f, am[5] * 0.125f);
}

extern "C" void kernel_launch(void* const* d_in, const int* in_sizes, int n_in,
                              void* d_out, int out_size, void* d_ws, size_t ws_size,
                              hipStream_t stream) {
    const float* x     = (const float*)d_in[0];
    const float* W_in  = (const float*)d_in[1];
    const float* b_in  = (const float*)d_in[2];
    const float* Wq    = (const float*)d_in[3];
    const float* bq    = (const float*)d_in[4];
    const float* Wk    = (const float*)d_in[5];
    const float* bk    = (const float*)d_in[6];
    const float* Wv    = (const float*)d_in[7];
    const float* bv    = (const float*)d_in[8];
    const float* Wo    = (const float*)d_in[9];
    const float* bo    = (const float*)d_in[10];
    const float* gamma = (const float*)d_in[11];
    const float* beta  = (const float*)d_in[12];
    float* ws  = (float*)d_ws;
    float* out = (float*)d_out;

    const int total = in_sizes[0];  // B*6 = 98304

    kA<<<192, 256, 0, stream>>>(W_in, b_in, gamma, beta, Wq, bq, Wk, bk, Wv, bv, ws, out);
    kB<<<8, 256, 0, stream>>>(out, Wo, ws);
    kC<<<(total + 255) / 256, 256, 0, stream>>>(x, ws, bo, out, total);
}